// Round 3
// baseline (445.244 us; speedup 1.0000x reference)
//
#include <hip/hip_runtime.h>
#include <hip/hip_bf16.h>
#include <math.h>

#define N_  512
#define D_  384
#define H_  12
#define DK_ 32
#define P_  128

typedef short short8 __attribute__((ext_vector_type(8)));
typedef float f32x4  __attribute__((ext_vector_type(4)));

static __device__ __forceinline__ unsigned short f2bf(float f) {
    union { float f; unsigned int u; } v; v.f = f;
    unsigned int r = (v.u + 0x7FFFu + ((v.u >> 16) & 1u)) >> 16;  // RNE
    return (unsigned short)r;
}

// ---------------------------------------------------------------------------
// K1: projections + affine. Grid (64, 5). Unchanged from R2.
// ---------------------------------------------------------------------------
__global__ __launch_bounds__(384) void k_proj(
    const float* __restrict__ x1d, const float* __restrict__ pose_t,
    const float* __restrict__ pose_r,
    const float* __restrict__ w_sq, const float* __restrict__ w_sk,
    const float* __restrict__ w_sv, const float* __restrict__ w_pq,
    const float* __restrict__ w_pk, const float* __restrict__ w_pv,
    float* __restrict__ qs, float* __restrict__ kst, float* __restrict__ vs,
    float* __restrict__ qp, float* __restrict__ kpt, float* __restrict__ vp)
{
    const int seg = blockIdx.y;
    const int i0  = blockIdx.x * 8;
    const int t   = threadIdx.x;

    __shared__ float raw[8][288];
    __shared__ float Rsh[8][9];
    __shared__ float Tsh[8][3];

    if (seg < 3) {
        const float* __restrict__ w = (seg == 0) ? w_sq : (seg == 1) ? w_sk : w_sv;
        float acc[8];
        #pragma unroll
        for (int r = 0; r < 8; ++r) acc[r] = 0.f;
        for (int d = 0; d < D_; d += 4) {
            float4 xr[8];
            #pragma unroll
            for (int r = 0; r < 8; ++r)
                xr[r] = *(const float4*)(x1d + (i0 + r) * D_ + d);
            #pragma unroll
            for (int e = 0; e < 4; ++e) {
                float wv = w[(d + e) * D_ + t];
                #pragma unroll
                for (int r = 0; r < 8; ++r)
                    acc[r] += ((const float*)&xr[r])[e] * wv;
            }
        }
        if (seg == 0) {
            #pragma unroll
            for (int r = 0; r < 8; ++r) qs[(i0 + r) * D_ + t] = acc[r];
        } else if (seg == 1) {
            *(float4*)(kst + t * N_ + i0)     = make_float4(acc[0], acc[1], acc[2], acc[3]);
            *(float4*)(kst + t * N_ + i0 + 4) = make_float4(acc[4], acc[5], acc[6], acc[7]);
        } else {
            #pragma unroll
            for (int r = 0; r < 8; ++r) vs[(i0 + r) * D_ + t] = acc[r];
        }
    } else {
        if (t < 72) Rsh[t / 9][t % 9] = pose_r[(i0 + t / 9) * 9 + t % 9];
        else if (t < 96) {
            int r = (t - 72) / 3, c = (t - 72) % 3;
            Tsh[r][c] = pose_t[(i0 + r) * 3 + c];
        }

        if (t < 288) {
            const float* __restrict__ w;
            int col, ldw;
            if (seg == 3) {
                if (t < 144) { w = w_pq; col = t;       ldw = 144; }
                else         { w = w_pk; col = t - 144; ldw = 144; }
            } else         { w = w_pv; col = t;       ldw = 288; }
            float acc[8];
            #pragma unroll
            for (int r = 0; r < 8; ++r) acc[r] = 0.f;
            for (int d = 0; d < D_; d += 4) {
                float4 xr[8];
                #pragma unroll
                for (int r = 0; r < 8; ++r)
                    xr[r] = *(const float4*)(x1d + (i0 + r) * D_ + d);
                #pragma unroll
                for (int e = 0; e < 4; ++e) {
                    float wv = w[(d + e) * ldw + col];
                    #pragma unroll
                    for (int r = 0; r < 8; ++r)
                        acc[r] += ((const float*)&xr[r])[e] * wv;
                }
            }
            #pragma unroll
            for (int r = 0; r < 8; ++r) raw[r][t] = acc[r];
        }
        __syncthreads();

        if (t < 288) {
            const int x3   = t % 3;
            const int base = t - x3;
            if (seg == 3) {
                const int c = (t < 144) ? t : t - 144;
                if (t < 144) {
                    #pragma unroll
                    for (int r = 0; r < 8; ++r) {
                        float g = Rsh[r][0 + x3] * raw[r][base]
                                + Rsh[r][3 + x3] * raw[r][base + 1]
                                + Rsh[r][6 + x3] * raw[r][base + 2] + Tsh[r][x3];
                        qp[(i0 + r) * 144 + c] = g;
                    }
                } else {
                    float g[8];
                    #pragma unroll
                    for (int r = 0; r < 8; ++r)
                        g[r] = Rsh[r][0 + x3] * raw[r][base]
                             + Rsh[r][3 + x3] * raw[r][base + 1]
                             + Rsh[r][6 + x3] * raw[r][base + 2] + Tsh[r][x3];
                    *(float4*)(kpt + c * N_ + i0)     = make_float4(g[0], g[1], g[2], g[3]);
                    *(float4*)(kpt + c * N_ + i0 + 4) = make_float4(g[4], g[5], g[6], g[7]);
                }
            } else {
                #pragma unroll
                for (int r = 0; r < 8; ++r) {
                    float g = Rsh[r][0 + x3] * raw[r][base]
                            + Rsh[r][3 + x3] * raw[r][base + 1]
                            + Rsh[r][6 + x3] * raw[r][base + 2] + Tsh[r][x3];
                    vp[(i0 + r) * 288 + t] = g;
                }
            }
        }
    }
}

// ---------------------------------------------------------------------------
// K2a: pair-bias logits via MFMA bf16 + fused x2d -> bf16 transposed copy.
// C[262144 x 12] = x2d[262144 x 128] @ w_pb[128 x 12], tiles of 16 pairs.
// Writes logits (pre-scaled), x2bT[i][p][j] bf16.
// ---------------------------------------------------------------------------
__global__ __launch_bounds__(256) void k_logits_pair(
    const float* __restrict__ x2d, const float* __restrict__ w_pb,
    float* __restrict__ logits, unsigned short* __restrict__ x2bT)
{
    const int t    = threadIdx.x;
    const int wid  = t >> 6;
    const int lane = t & 63;
    const int quad = lane >> 4;
    const int col  = lane & 15;
    const float pair_w = 0.57735027f;

    // B fragments: w_pb[p][h], n=col (h), k=quad*8+jj (p). Zero-pad h>=12.
    short8 bfr[4];
    #pragma unroll
    for (int kt = 0; kt < 4; ++kt) {
        #pragma unroll
        for (int jj = 0; jj < 8; ++jj) {
            int p = kt * 32 + quad * 8 + jj;
            bfr[kt][jj] = (col < 12) ? (short)f2bf(w_pb[p * 12 + col]) : (short)0;
        }
    }

    #pragma unroll
    for (int s = 0; s < 2; ++s) {
        const int T  = blockIdx.x * 8 + wid * 2 + s;   // M-tile index
        const int i  = T >> 5;                          // 32 tiles per i
        const int j0 = (T & 31) << 4;
        const float* xrow = x2d + ((size_t)(i * N_) + j0 + col) * P_;

        f32x4 acc = {0.f, 0.f, 0.f, 0.f};
        #pragma unroll
        for (int kt = 0; kt < 4; ++kt) {
            const int k0 = kt * 32 + quad * 8;
            float4 f0 = *(const float4*)(xrow + k0);
            float4 f1 = *(const float4*)(xrow + k0 + 4);
            short8 afr;
            afr[0] = (short)f2bf(f0.x); afr[1] = (short)f2bf(f0.y);
            afr[2] = (short)f2bf(f0.z); afr[3] = (short)f2bf(f0.w);
            afr[4] = (short)f2bf(f1.x); afr[5] = (short)f2bf(f1.y);
            afr[6] = (short)f2bf(f1.z); afr[7] = (short)f2bf(f1.w);
            // transposed bf16 store: x2bT[i][p][j]
            #pragma unroll
            for (int jj = 0; jj < 8; ++jj)
                x2bT[((size_t)i * P_ + k0 + jj) * N_ + j0 + col] = (unsigned short)afr[jj];
            acc = __builtin_amdgcn_mfma_f32_16x16x32_bf16(afr, bfr[kt], acc, 0, 0, 0);
        }
        if (col < 12) {
            #pragma unroll
            for (int r = 0; r < 4; ++r) {
                int j = j0 + quad * 4 + r;
                logits[((size_t)(col * N_ + i)) * N_ + j] = pair_w * acc[r];
            }
        }
    }
}

// ---------------------------------------------------------------------------
// K2b: scalar + point + bias logits, ACCUMULATES onto pair logits.
// ---------------------------------------------------------------------------
__global__ __launch_bounds__(256) void k_logits_sp(
    const float* __restrict__ qs, const float* __restrict__ kst,
    const float* __restrict__ qp, const float* __restrict__ kpt,
    const float* __restrict__ bias, const float* __restrict__ tpw,
    float* __restrict__ logits)
{
    const int h  = blockIdx.x / 128;
    const int i0 = (blockIdx.x % 128) * 4;
    const int t  = threadIdx.x;
    __shared__ float qsh[4][32];
    __shared__ float qph[4][12];
    if (t < 128) { int il = t / 32, c = t % 32; qsh[il][c] = qs[(i0+il) * D_ + h*32 + c]; }
    else if (t < 176) { int r = t - 128; int il = r / 12, c = r % 12; qph[il][c] = qp[(i0+il)*144 + h*12 + c]; }
    const float pwh = 0.13608276f * log1pf(expf(tpw[h]));
    const float scalar_w = 0.10206207f;
    __syncthreads();

    for (int jh = 0; jh < 2; ++jh) {
        int j = t + jh * 256;
        float kv[32];
        #pragma unroll
        for (int c = 0; c < 32; ++c) kv[c] = kst[(h*32 + c) * N_ + j];
        float kp[12];
        #pragma unroll
        for (int c = 0; c < 12; ++c) kp[c] = kpt[(h*12 + c) * N_ + j];

        #pragma unroll
        for (int il = 0; il < 4; ++il) {
            float s = 0.f;
            #pragma unroll
            for (int c = 0; c < 32; ++c) s += qsh[il][c] * kv[c];
            float dsum = 0.f;
            #pragma unroll
            for (int p = 0; p < 4; ++p) {
                float dx = qph[il][p*3+0] - kp[p*3+0];
                float dy = qph[il][p*3+1] - kp[p*3+1];
                float dz = qph[il][p*3+2] - kp[p*3+2];
                dsum += sqrtf(dx*dx + dy*dy + dz*dz);
            }
            size_t idx = ((size_t)(h * N_ + (i0+il))) * N_ + j;
            logits[idx] += scalar_w * s - 0.5f * pwh * dsum + bias[(i0+il) * N_ + j];
        }
    }
}

// ---------------------------------------------------------------------------
// K3: softmax. Grid 16*512; h>=12 blocks only zero the bf16 attn plane.
// Writes fp32 attn in place + bf16 attn copy (16 h-planes).
// ---------------------------------------------------------------------------
__global__ __launch_bounds__(256) void k_softmax(float* __restrict__ logits,
                                                 unsigned short* __restrict__ attn_bf)
{
    const int row = blockIdx.x;       // h*512 + i, h in [0,16)
    const int t = threadIdx.x;
    if (row >= 12 * N_) {
        attn_bf[(size_t)row * N_ + t]       = 0;
        attn_bf[(size_t)row * N_ + t + 256] = 0;
        return;
    }
    float* ptr = logits + (size_t)row * N_;
    __shared__ float red[256];

    float a = ptr[t], b = ptr[t + 256];
    red[t] = fmaxf(a, b);
    __syncthreads();
    for (int s = 128; s > 0; s >>= 1) {
        if (t < s) red[t] = fmaxf(red[t], red[t + s]);
        __syncthreads();
    }
    float m = red[0];
    __syncthreads();
    float ea = __expf(a - m), eb = __expf(b - m);
    red[t] = ea + eb;
    __syncthreads();
    for (int s = 128; s > 0; s >>= 1) {
        if (t < s) red[t] += red[t + s];
        __syncthreads();
    }
    float inv = 1.0f / red[0];
    float pa = ea * inv, pb = eb * inv;
    ptr[t]       = pa;
    ptr[t + 256] = pb;
    attn_bf[(size_t)row * N_ + t]       = f2bf(pa);
    attn_bf[(size_t)row * N_ + t + 256] = f2bf(pb);
}

// ---------------------------------------------------------------------------
// K4: tmp[i][h*128+p] = sum_j attn[h,i,j] * x2d[i,j,p] via MFMA bf16.
// Per block (one i): A = attn_bf (M=16 h, K=512 j), B = x2bT[i] (K=512 j,
// N=128 p). Wave w owns n-tiles 2w, 2w+1.
// ---------------------------------------------------------------------------
__global__ __launch_bounds__(256) void k_tmp(
    const unsigned short* __restrict__ attn_bf,
    const unsigned short* __restrict__ x2bT,
    float* __restrict__ tmp)
{
    const int i    = blockIdx.x;
    const int t    = threadIdx.x;
    const int wid  = t >> 6;
    const int lane = t & 63;
    const int quad = lane >> 4;
    const int col  = lane & 15;
    const int p0 = wid * 32, p1 = p0 + 16;

    f32x4 acc0 = {0.f, 0.f, 0.f, 0.f};
    f32x4 acc1 = {0.f, 0.f, 0.f, 0.f};

    const unsigned short* arow = attn_bf + ((size_t)col * N_ + i) * N_;
    const unsigned short* b0r  = x2bT + ((size_t)i * P_ + p0 + col) * N_;
    const unsigned short* b1r  = x2bT + ((size_t)i * P_ + p1 + col) * N_;

    #pragma unroll 4
    for (int kt = 0; kt < 16; ++kt) {
        const int k0 = kt * 32 + quad * 8;
        short8 a  = *(const short8*)(arow + k0);
        short8 b0 = *(const short8*)(b0r + k0);
        short8 b1 = *(const short8*)(b1r + k0);
        acc0 = __builtin_amdgcn_mfma_f32_16x16x32_bf16(a, b0, acc0, 0, 0, 0);
        acc1 = __builtin_amdgcn_mfma_f32_16x16x32_bf16(a, b1, acc1, 0, 0, 0);
    }
    #pragma unroll
    for (int r = 0; r < 4; ++r) {
        int h = quad * 4 + r;
        if (h < 12) {
            tmp[(size_t)i * 1536 + h * P_ + p0 + col] = acc0[r];
            tmp[(size_t)i * 1536 + h * P_ + p1 + col] = acc1[r];
        }
    }
}

__global__ __launch_bounds__(256) void k_aggr_v(
    const float* __restrict__ attn, const float* __restrict__ vs,
    const float* __restrict__ vp, float* __restrict__ feat,
    float* __restrict__ outpg)
{
    const int h  = blockIdx.x / 128;
    const int i0 = (blockIdx.x % 128) * 4;
    const int t  = threadIdx.x;
    __shared__ float at[4][N_];
    for (int idx = t; idx < 4 * N_; idx += 256) {
        int il = idx / N_, j = idx % N_;
        at[il][j] = attn[((size_t)(h * N_ + i0 + il)) * N_ + j];
    }
    __syncthreads();

    const int vi = t & 63, ig = t >> 6;
    if (vi < 56) {
        const float* src;
        int stride;
        float* dst;
        if (vi < 32) {
            src = vs + h * 32 + vi; stride = D_;
            dst = feat + (size_t)(i0 + ig) * 1152 + h * 32 + vi;
        } else {
            int r = vi - 32;
            src = vp + h * 24 + r; stride = 288;
            dst = outpg + ((i0 + ig) * 12 + h) * 24 + r;
        }
        float acc = 0.f;
        #pragma unroll 4
        for (int j = 0; j < N_; ++j) acc += at[ig][j] * src[(size_t)j * stride];
        *dst = acc;
    }
}

__global__ __launch_bounds__(384) void k_feat(
    const float* __restrict__ tmp, const float* __restrict__ outpg,
    const float* __restrict__ pose_t, const float* __restrict__ pose_r,
    const float* __restrict__ w_pairv, float* __restrict__ feat)
{
    const int i = blockIdx.x;
    const int t = threadIdx.x;
    __shared__ float tsh[1536];
    __shared__ float pg[288];
    __shared__ float pl[288];
    __shared__ float Rsh[9], Tsh[3];

    for (int idx = t; idx < 1536; idx += 384) tsh[idx] = tmp[(size_t)i * 1536 + idx];
    if (t < 288) pg[t] = outpg[i * 288 + t];
    if (t < 9) Rsh[t] = pose_r[i * 9 + t];
    if (t < 3) Tsh[t] = pose_t[i * 3 + t];
    __syncthreads();

    {
        int h = t >> 5;
        const float* ts = tsh + h * 128;
        float acc = 0.f;
        #pragma unroll 4
        for (int p = 0; p < 128; ++p) acc += ts[p] * w_pairv[p * D_ + t];
        feat[(size_t)i * 1152 + 672 + t] = acc;
    }
    if (t < 288) {
        int x3 = t % 3, base = t - x3;
        float g0 = pg[base + 0] - Tsh[0];
        float g1 = pg[base + 1] - Tsh[1];
        float g2 = pg[base + 2] - Tsh[2];
        float v = Rsh[x3*3+0]*g0 + Rsh[x3*3+1]*g1 + Rsh[x3*3+2]*g2;
        pl[t] = v;
        feat[(size_t)i * 1152 + 384 + t] = v;
    }
    __syncthreads();
    if (t < 96) {
        float a = pl[t*3], b = pl[t*3+1], c = pl[t*3+2];
        feat[(size_t)i * 1152 + 1056 + t] = sqrtf(a*a + b*b + c*c);
    }
}

__global__ __launch_bounds__(384) void k_out_part(
    const float* __restrict__ feat, const float* __restrict__ w_out,
    float* __restrict__ part)
{
    const int kc = blockIdx.x >> 6;
    const int i0 = (blockIdx.x & 63) * 8;
    const int t  = threadIdx.x;
    const int k0 = kc * 144;

    float acc[8];
    #pragma unroll
    for (int r = 0; r < 8; ++r) acc[r] = 0.f;

    for (int d = 0; d < 144; d += 4) {
        float4 fr[8];
        #pragma unroll
        for (int r = 0; r < 8; ++r)
            fr[r] = *(const float4*)(feat + (size_t)(i0 + r) * 1152 + k0 + d);
        #pragma unroll
        for (int e = 0; e < 4; ++e) {
            float wv = w_out[(size_t)(k0 + d + e) * D_ + t];
            #pragma unroll
            for (int r = 0; r < 8; ++r)
                acc[r] += ((const float*)&fr[r])[e] * wv;
        }
    }
    #pragma unroll
    for (int r = 0; r < 8; ++r)
        part[((size_t)kc * N_ + i0 + r) * D_ + t] = acc[r];
}

__global__ __launch_bounds__(256) void k_out_red(
    const float* __restrict__ part, const float* __restrict__ b_out,
    float* __restrict__ out)
{
    const int idx = blockIdx.x * 256 + threadIdx.x;
    float s = b_out[idx % D_];
    #pragma unroll
    for (int kc = 0; kc < 8; ++kc) s += part[(size_t)kc * (N_ * D_) + idx];
    out[idx] = s;
}

extern "C" void kernel_launch(void* const* d_in, const int* in_sizes, int n_in,
                              void* d_out, int out_size, void* d_ws, size_t ws_size,
                              hipStream_t stream)
{
    (void)in_sizes; (void)n_in; (void)out_size; (void)ws_size;
    const float* x1d     = (const float*)d_in[0];
    const float* x2d     = (const float*)d_in[1];
    const float* pose_t  = (const float*)d_in[2];
    const float* pose_r  = (const float*)d_in[3];
    const float* bias    = (const float*)d_in[4];
    const float* w_sq    = (const float*)d_in[5];
    const float* w_sk    = (const float*)d_in[6];
    const float* w_sv    = (const float*)d_in[7];
    const float* w_pb    = (const float*)d_in[8];
    const float* w_pq    = (const float*)d_in[9];
    const float* w_pk    = (const float*)d_in[10];
    const float* w_pv    = (const float*)d_in[11];
    const float* tpw     = (const float*)d_in[12];
    const float* w_pairv = (const float*)d_in[13];
    const float* w_out   = (const float*)d_in[14];
    const float* b_out   = (const float*)d_in[15];
    float* out = (float*)d_out;

    float* ws = (float*)d_ws;
    float* qs     = ws;
    float* kst    = qs     + 196608;
    float* vs     = kst    + 196608;
    float* qp     = vs     + 196608;
    float* kpt    = qp     + 73728;
    float* vp     = kpt    + 73728;
    float* logits = vp     + 147456;
    float* tmp    = logits + 3145728;
    float* outpg  = tmp    + 786432;
    float* feat   = outpg  + 147456;
    float* part   = feat   + 589824;   // 1572864 floats
    unsigned short* attn_bf = (unsigned short*)(part + 1572864);  // 16*512*512 bf16
    unsigned short* x2bT    = attn_bf + (size_t)16 * N_ * N_;     // 512*128*512 bf16

    hipLaunchKernelGGL(k_logits_pair, dim3(2048), dim3(256), 0, stream,
                       x2d, w_pb, logits, x2bT);
    hipLaunchKernelGGL(k_proj, dim3(64, 5), dim3(384), 0, stream,
                       x1d, pose_t, pose_r, w_sq, w_sk, w_sv, w_pq, w_pk, w_pv,
                       qs, kst, vs, qp, kpt, vp);
    hipLaunchKernelGGL(k_logits_sp, dim3(12 * 128), dim3(256), 0, stream,
                       qs, kst, qp, kpt, bias, tpw, logits);
    hipLaunchKernelGGL(k_softmax, dim3(16 * N_), dim3(256), 0, stream,
                       logits, attn_bf);
    hipLaunchKernelGGL(k_tmp, dim3(N_), dim3(256), 0, stream,
                       attn_bf, x2bT, tmp);
    hipLaunchKernelGGL(k_aggr_v, dim3(12 * 128), dim3(256), 0, stream,
                       logits, vs, vp, feat, outpg);
    hipLaunchKernelGGL(k_feat, dim3(N_), dim3(384), 0, stream,
                       tmp, outpg, pose_t, pose_r, w_pairv, feat);
    hipLaunchKernelGGL(k_out_part, dim3(512), dim3(384), 0, stream,
                       feat, w_out, part);
    hipLaunchKernelGGL(k_out_red, dim3(768), dim3(256), 0, stream,
                       part, b_out, out);
}

// Round 4
// 395.334 us; speedup vs baseline: 1.1262x; 1.1262x over previous
//
#include <hip/hip_runtime.h>
#include <hip/hip_bf16.h>
#include <math.h>

#define N_  512
#define D_  384
#define H_  12
#define DK_ 32
#define P_  128

typedef short short8 __attribute__((ext_vector_type(8)));
typedef float f32x4  __attribute__((ext_vector_type(4)));

static __device__ __forceinline__ unsigned short f2bf(float f) {
    union { float f; unsigned int u; } v; v.f = f;
    unsigned int r = (v.u + 0x7FFFu + ((v.u >> 16) & 1u)) >> 16;  // RNE
    return (unsigned short)r;
}

// ---------------------------------------------------------------------------
// K1: projections + affine. Grid (64, 5): blockIdx.y = segment
// {0:w_sq, 1:w_sk, 2:w_sv->vcatT, 3:w_pq+w_pk, 4:w_pv->vcatT}.
// vcatT[h][c][j] bf16, c in [0,64): 0..31 = v_s cols, 32..55 = v_p (global),
// 56..63 never read.
// ---------------------------------------------------------------------------
__global__ __launch_bounds__(384) void k_proj(
    const float* __restrict__ x1d, const float* __restrict__ pose_t,
    const float* __restrict__ pose_r,
    const float* __restrict__ w_sq, const float* __restrict__ w_sk,
    const float* __restrict__ w_sv, const float* __restrict__ w_pq,
    const float* __restrict__ w_pk, const float* __restrict__ w_pv,
    float* __restrict__ qs, float* __restrict__ kst,
    float* __restrict__ qp, float* __restrict__ kpt,
    unsigned short* __restrict__ vcatT)
{
    const int seg = blockIdx.y;
    const int i0  = blockIdx.x * 8;
    const int t   = threadIdx.x;

    __shared__ float raw[8][288];
    __shared__ float Rsh[8][9];
    __shared__ float Tsh[8][3];

    if (seg < 3) {
        const float* __restrict__ w = (seg == 0) ? w_sq : (seg == 1) ? w_sk : w_sv;
        float acc[8];
        #pragma unroll
        for (int r = 0; r < 8; ++r) acc[r] = 0.f;
        for (int d = 0; d < D_; d += 4) {
            float4 xr[8];
            #pragma unroll
            for (int r = 0; r < 8; ++r)
                xr[r] = *(const float4*)(x1d + (i0 + r) * D_ + d);
            #pragma unroll
            for (int e = 0; e < 4; ++e) {
                float wv = w[(d + e) * D_ + t];
                #pragma unroll
                for (int r = 0; r < 8; ++r)
                    acc[r] += ((const float*)&xr[r])[e] * wv;
            }
        }
        if (seg == 0) {
            #pragma unroll
            for (int r = 0; r < 8; ++r) qs[(i0 + r) * D_ + t] = acc[r];
        } else if (seg == 1) {
            *(float4*)(kst + t * N_ + i0)     = make_float4(acc[0], acc[1], acc[2], acc[3]);
            *(float4*)(kst + t * N_ + i0 + 4) = make_float4(acc[4], acc[5], acc[6], acc[7]);
        } else {
            // v_s -> vcatT[h][c][i0..i0+7] bf16
            int h = t >> 5, c = t & 31;
            short8 sv;
            #pragma unroll
            for (int r = 0; r < 8; ++r) sv[r] = (short)f2bf(acc[r]);
            *(short8*)(vcatT + ((size_t)h * 64 + c) * N_ + i0) = sv;
        }
    } else {
        if (t < 72) Rsh[t / 9][t % 9] = pose_r[(i0 + t / 9) * 9 + t % 9];
        else if (t < 96) {
            int r = (t - 72) / 3, c = (t - 72) % 3;
            Tsh[r][c] = pose_t[(i0 + r) * 3 + c];
        }

        if (t < 288) {
            const float* __restrict__ w;
            int col, ldw;
            if (seg == 3) {
                if (t < 144) { w = w_pq; col = t;       ldw = 144; }
                else         { w = w_pk; col = t - 144; ldw = 144; }
            } else         { w = w_pv; col = t;       ldw = 288; }
            float acc[8];
            #pragma unroll
            for (int r = 0; r < 8; ++r) acc[r] = 0.f;
            for (int d = 0; d < D_; d += 4) {
                float4 xr[8];
                #pragma unroll
                for (int r = 0; r < 8; ++r)
                    xr[r] = *(const float4*)(x1d + (i0 + r) * D_ + d);
                #pragma unroll
                for (int e = 0; e < 4; ++e) {
                    float wv = w[(d + e) * ldw + col];
                    #pragma unroll
                    for (int r = 0; r < 8; ++r)
                        acc[r] += ((const float*)&xr[r])[e] * wv;
                }
            }
            #pragma unroll
            for (int r = 0; r < 8; ++r) raw[r][t] = acc[r];
        }
        __syncthreads();

        if (t < 288) {
            const int x3   = t % 3;
            const int base = t - x3;
            if (seg == 3) {
                const int c = (t < 144) ? t : t - 144;
                if (t < 144) {
                    #pragma unroll
                    for (int r = 0; r < 8; ++r) {
                        float g = Rsh[r][0 + x3] * raw[r][base]
                                + Rsh[r][3 + x3] * raw[r][base + 1]
                                + Rsh[r][6 + x3] * raw[r][base + 2] + Tsh[r][x3];
                        qp[(i0 + r) * 144 + c] = g;
                    }
                } else {
                    float g[8];
                    #pragma unroll
                    for (int r = 0; r < 8; ++r)
                        g[r] = Rsh[r][0 + x3] * raw[r][base]
                             + Rsh[r][3 + x3] * raw[r][base + 1]
                             + Rsh[r][6 + x3] * raw[r][base + 2] + Tsh[r][x3];
                    *(float4*)(kpt + c * N_ + i0)     = make_float4(g[0], g[1], g[2], g[3]);
                    *(float4*)(kpt + c * N_ + i0 + 4) = make_float4(g[4], g[5], g[6], g[7]);
                }
            } else {
                // v_p global frame -> vcatT[h][32+pc][i0..i0+7] bf16
                int h = t / 24, pc = t % 24;
                short8 sv;
                #pragma unroll
                for (int r = 0; r < 8; ++r) {
                    float g = Rsh[r][0 + x3] * raw[r][base]
                            + Rsh[r][3 + x3] * raw[r][base + 1]
                            + Rsh[r][6 + x3] * raw[r][base + 2] + Tsh[r][x3];
                    sv[r] = (short)f2bf(g);
                }
                *(short8*)(vcatT + ((size_t)h * 64 + 32 + pc) * N_ + i0) = sv;
            }
        }
    }
}

// ---------------------------------------------------------------------------
// K2a: pair-bias logits via MFMA bf16 (pure GEMM, no side outputs).
// ---------------------------------------------------------------------------
__global__ __launch_bounds__(256) void k_logits_pair(
    const float* __restrict__ x2d, const float* __restrict__ w_pb,
    float* __restrict__ logits)
{
    const int t    = threadIdx.x;
    const int wid  = t >> 6;
    const int lane = t & 63;
    const int quad = lane >> 4;
    const int col  = lane & 15;
    const float pair_w = 0.57735027f;

    short8 bfr[4];
    #pragma unroll
    for (int kt = 0; kt < 4; ++kt) {
        #pragma unroll
        for (int jj = 0; jj < 8; ++jj) {
            int p = kt * 32 + quad * 8 + jj;
            bfr[kt][jj] = (col < 12) ? (short)f2bf(w_pb[p * 12 + col]) : (short)0;
        }
    }

    #pragma unroll
    for (int s = 0; s < 2; ++s) {
        const int T  = blockIdx.x * 8 + wid * 2 + s;
        const int i  = T >> 5;
        const int j0 = (T & 31) << 4;
        const float* xrow = x2d + ((size_t)(i * N_) + j0 + col) * P_;

        f32x4 acc = {0.f, 0.f, 0.f, 0.f};
        #pragma unroll
        for (int kt = 0; kt < 4; ++kt) {
            const int k0 = kt * 32 + quad * 8;
            float4 f0 = *(const float4*)(xrow + k0);
            float4 f1 = *(const float4*)(xrow + k0 + 4);
            short8 afr;
            afr[0] = (short)f2bf(f0.x); afr[1] = (short)f2bf(f0.y);
            afr[2] = (short)f2bf(f0.z); afr[3] = (short)f2bf(f0.w);
            afr[4] = (short)f2bf(f1.x); afr[5] = (short)f2bf(f1.y);
            afr[6] = (short)f2bf(f1.z); afr[7] = (short)f2bf(f1.w);
            acc = __builtin_amdgcn_mfma_f32_16x16x32_bf16(afr, bfr[kt], acc, 0, 0, 0);
        }
        if (col < 12) {
            #pragma unroll
            for (int r = 0; r < 4; ++r) {
                int j = j0 + quad * 4 + r;
                logits[((size_t)(col * N_ + i)) * N_ + j] = pair_w * acc[r];
            }
        }
    }
}

// ---------------------------------------------------------------------------
// K2b: scalar + point + bias logits, accumulates onto pair logits.
// ---------------------------------------------------------------------------
__global__ __launch_bounds__(256) void k_logits_sp(
    const float* __restrict__ qs, const float* __restrict__ kst,
    const float* __restrict__ qp, const float* __restrict__ kpt,
    const float* __restrict__ bias, const float* __restrict__ tpw,
    float* __restrict__ logits)
{
    const int h  = blockIdx.x / 128;
    const int i0 = (blockIdx.x % 128) * 4;
    const int t  = threadIdx.x;
    __shared__ float qsh[4][32];
    __shared__ float qph[4][12];
    if (t < 128) { int il = t / 32, c = t % 32; qsh[il][c] = qs[(i0+il) * D_ + h*32 + c]; }
    else if (t < 176) { int r = t - 128; int il = r / 12, c = r % 12; qph[il][c] = qp[(i0+il)*144 + h*12 + c]; }
    const float pwh = 0.13608276f * log1pf(expf(tpw[h]));
    const float scalar_w = 0.10206207f;
    __syncthreads();

    for (int jh = 0; jh < 2; ++jh) {
        int j = t + jh * 256;
        float kv[32];
        #pragma unroll
        for (int c = 0; c < 32; ++c) kv[c] = kst[(h*32 + c) * N_ + j];
        float kp[12];
        #pragma unroll
        for (int c = 0; c < 12; ++c) kp[c] = kpt[(h*12 + c) * N_ + j];

        #pragma unroll
        for (int il = 0; il < 4; ++il) {
            float s = 0.f;
            #pragma unroll
            for (int c = 0; c < 32; ++c) s += qsh[il][c] * kv[c];
            float dsum = 0.f;
            #pragma unroll
            for (int p = 0; p < 4; ++p) {
                float dx = qph[il][p*3+0] - kp[p*3+0];
                float dy = qph[il][p*3+1] - kp[p*3+1];
                float dz = qph[il][p*3+2] - kp[p*3+2];
                dsum += sqrtf(dx*dx + dy*dy + dz*dz);
            }
            size_t idx = ((size_t)(h * N_ + (i0+il))) * N_ + j;
            logits[idx] += scalar_w * s - 0.5f * pwh * dsum + bias[(i0+il) * N_ + j];
        }
    }
}

// ---------------------------------------------------------------------------
// K3: softmax (in-place fp32) + bf16 attn copy.
// ---------------------------------------------------------------------------
__global__ __launch_bounds__(256) void k_softmax(float* __restrict__ logits,
                                                 unsigned short* __restrict__ attn_bf)
{
    const int row = blockIdx.x;       // h*512 + i
    const int t = threadIdx.x;
    float* ptr = logits + (size_t)row * N_;
    __shared__ float red[256];

    float a = ptr[t], b = ptr[t + 256];
    red[t] = fmaxf(a, b);
    __syncthreads();
    for (int s = 128; s > 0; s >>= 1) {
        if (t < s) red[t] = fmaxf(red[t], red[t + s]);
        __syncthreads();
    }
    float m = red[0];
    __syncthreads();
    float ea = __expf(a - m), eb = __expf(b - m);
    red[t] = ea + eb;
    __syncthreads();
    for (int s = 128; s > 0; s >>= 1) {
        if (t < s) red[t] += red[t + s];
        __syncthreads();
    }
    float inv = 1.0f / red[0];
    float pa = ea * inv, pb = eb * inv;
    ptr[t]       = pa;
    ptr[t + 256] = pb;
    attn_bf[(size_t)row * N_ + t]       = f2bf(pa);
    attn_bf[(size_t)row * N_ + t + 256] = f2bf(pb);
}

// ---------------------------------------------------------------------------
// K4: tmp[i][h*128+p] = sum_j attn[h,i,j] * x2d[i,j,p].  (R2 VALU form —
// x2d second pass is L3-warm; compute is only 0.86 GFLOP.)
// ---------------------------------------------------------------------------
__global__ __launch_bounds__(256) void k_tmp(
    const float* __restrict__ attn, const float* __restrict__ x2d,
    float* __restrict__ tmp)
{
    const int i = blockIdx.x;
    const int t = threadIdx.x;
    __shared__ float4 at[N_][3];
    __shared__ float red[2][1536];

    for (int idx = t; idx < 12 * N_; idx += 256) {
        int h = idx / N_, j = idx % N_;
        ((float*)&at[j][h >> 2])[h & 3] = attn[((size_t)(h * N_ + i)) * N_ + j];
    }
    __syncthreads();

    const int p = t & 127, jh = t >> 7;
    float acc[12];
    #pragma unroll
    for (int h = 0; h < 12; ++h) acc[h] = 0.f;
    const float* xb = x2d + (size_t)i * N_ * P_;

    #pragma unroll 4
    for (int j = jh; j < N_; j += 2) {
        float x = xb[j * P_ + p];
        float4 a0 = at[j][0], a1 = at[j][1], a2 = at[j][2];
        acc[0] += a0.x*x; acc[1] += a0.y*x; acc[2]  += a0.z*x; acc[3]  += a0.w*x;
        acc[4] += a1.x*x; acc[5] += a1.y*x; acc[6]  += a1.z*x; acc[7]  += a1.w*x;
        acc[8] += a2.x*x; acc[9] += a2.y*x; acc[10] += a2.z*x; acc[11] += a2.w*x;
    }
    #pragma unroll
    for (int h = 0; h < 12; ++h) red[jh][h * 128 + p] = acc[h];
    __syncthreads();
    for (int idx = t; idx < 1536; idx += 256)
        tmp[(size_t)i * 1536 + idx] = red[0][idx] + red[1][idx];
}

// ---------------------------------------------------------------------------
// K5: attn @ [v_s | v_p] via MFMA bf16. Grid 384 = (h, 16-row m-tile).
// Wave w = n-tile w (cols w*16..w*16+15 of the 56 used).
// ---------------------------------------------------------------------------
__global__ __launch_bounds__(256) void k_aggr(
    const unsigned short* __restrict__ attn_bf,
    const unsigned short* __restrict__ vcatT,
    float* __restrict__ feat, float* __restrict__ outpg)
{
    const int h  = blockIdx.x >> 5;
    const int i0 = (blockIdx.x & 31) << 4;
    const int t    = threadIdx.x;
    const int wid  = t >> 6;
    const int lane = t & 63;
    const int quad = lane >> 4;
    const int col  = lane & 15;
    const int c    = wid * 16 + col;
    const bool cvalid = (c < 56);

    const unsigned short* arow = attn_bf + ((size_t)(h * N_ + i0 + col)) * N_;
    const unsigned short* brow = vcatT + ((size_t)h * 64 + c) * N_;

    f32x4 acc = {0.f, 0.f, 0.f, 0.f};
    #pragma unroll
    for (int kt = 0; kt < 16; ++kt) {
        const int k0 = kt * 32 + quad * 8;
        short8 a = *(const short8*)(arow + k0);
        short8 b;
        if (cvalid) b = *(const short8*)(brow + k0);
        else { b[0]=0;b[1]=0;b[2]=0;b[3]=0;b[4]=0;b[5]=0;b[6]=0;b[7]=0; }
        acc = __builtin_amdgcn_mfma_f32_16x16x32_bf16(a, b, acc, 0, 0, 0);
    }
    #pragma unroll
    for (int r = 0; r < 4; ++r) {
        int i = i0 + quad * 4 + r;
        if (c < 32)       feat[(size_t)i * 1152 + h * 32 + c] = acc[r];
        else if (c < 56)  outpg[((size_t)i * 12 + h) * 24 + (c - 32)] = acc[r];
    }
}

__global__ __launch_bounds__(384) void k_feat(
    const float* __restrict__ tmp, const float* __restrict__ outpg,
    const float* __restrict__ pose_t, const float* __restrict__ pose_r,
    const float* __restrict__ w_pairv, float* __restrict__ feat)
{
    const int i = blockIdx.x;
    const int t = threadIdx.x;
    __shared__ float tsh[1536];
    __shared__ float pg[288];
    __shared__ float pl[288];
    __shared__ float Rsh[9], Tsh[3];

    for (int idx = t; idx < 1536; idx += 384) tsh[idx] = tmp[(size_t)i * 1536 + idx];
    if (t < 288) pg[t] = outpg[i * 288 + t];
    if (t < 9) Rsh[t] = pose_r[i * 9 + t];
    if (t < 3) Tsh[t] = pose_t[i * 3 + t];
    __syncthreads();

    {
        int h = t >> 5;
        const float* ts = tsh + h * 128;
        float acc = 0.f;
        #pragma unroll 4
        for (int p = 0; p < 128; ++p) acc += ts[p] * w_pairv[p * D_ + t];
        feat[(size_t)i * 1152 + 672 + t] = acc;
    }
    if (t < 288) {
        int x3 = t % 3, base = t - x3;
        float g0 = pg[base + 0] - Tsh[0];
        float g1 = pg[base + 1] - Tsh[1];
        float g2 = pg[base + 2] - Tsh[2];
        float v = Rsh[x3*3+0]*g0 + Rsh[x3*3+1]*g1 + Rsh[x3*3+2]*g2;
        pl[t] = v;
        feat[(size_t)i * 1152 + 384 + t] = v;
    }
    __syncthreads();
    if (t < 96) {
        float a = pl[t*3], b = pl[t*3+1], c = pl[t*3+2];
        feat[(size_t)i * 1152 + 1056 + t] = sqrtf(a*a + b*b + c*c);
    }
}

__global__ __launch_bounds__(384) void k_out_part(
    const float* __restrict__ feat, const float* __restrict__ w_out,
    float* __restrict__ part)
{
    const int kc = blockIdx.x >> 6;
    const int i0 = (blockIdx.x & 63) * 8;
    const int t  = threadIdx.x;
    const int k0 = kc * 144;

    float acc[8];
    #pragma unroll
    for (int r = 0; r < 8; ++r) acc[r] = 0.f;

    for (int d = 0; d < 144; d += 4) {
        float4 fr[8];
        #pragma unroll
        for (int r = 0; r < 8; ++r)
            fr[r] = *(const float4*)(feat + (size_t)(i0 + r) * 1152 + k0 + d);
        #pragma unroll
        for (int e = 0; e < 4; ++e) {
            float wv = w_out[(size_t)(k0 + d + e) * D_ + t];
            #pragma unroll
            for (int r = 0; r < 8; ++r)
                acc[r] += ((const float*)&fr[r])[e] * wv;
        }
    }
    #pragma unroll
    for (int r = 0; r < 8; ++r)
        part[((size_t)kc * N_ + i0 + r) * D_ + t] = acc[r];
}

__global__ __launch_bounds__(256) void k_out_red(
    const float* __restrict__ part, const float* __restrict__ b_out,
    float* __restrict__ out)
{
    const int idx = blockIdx.x * 256 + threadIdx.x;
    float s = b_out[idx % D_];
    #pragma unroll
    for (int kc = 0; kc < 8; ++kc) s += part[(size_t)kc * (N_ * D_) + idx];
    out[idx] = s;
}

extern "C" void kernel_launch(void* const* d_in, const int* in_sizes, int n_in,
                              void* d_out, int out_size, void* d_ws, size_t ws_size,
                              hipStream_t stream)
{
    (void)in_sizes; (void)n_in; (void)out_size; (void)ws_size;
    const float* x1d     = (const float*)d_in[0];
    const float* x2d     = (const float*)d_in[1];
    const float* pose_t  = (const float*)d_in[2];
    const float* pose_r  = (const float*)d_in[3];
    const float* bias    = (const float*)d_in[4];
    const float* w_sq    = (const float*)d_in[5];
    const float* w_sk    = (const float*)d_in[6];
    const float* w_sv    = (const float*)d_in[7];
    const float* w_pb    = (const float*)d_in[8];
    const float* w_pq    = (const float*)d_in[9];
    const float* w_pk    = (const float*)d_in[10];
    const float* w_pv    = (const float*)d_in[11];
    const float* tpw     = (const float*)d_in[12];
    const float* w_pairv = (const float*)d_in[13];
    const float* w_out   = (const float*)d_in[14];
    const float* b_out   = (const float*)d_in[15];
    float* out = (float*)d_out;

    float* ws = (float*)d_ws;
    float* qs     = ws;
    float* kst    = qs     + 196608;
    float* qp     = kst    + 196608;
    float* kpt    = qp     + 73728;
    float* logits = kpt    + 73728;
    float* tmp    = logits + 3145728;
    float* outpg  = tmp    + 786432;
    float* feat   = outpg  + 147456;
    float* part   = feat   + 589824;   // 1572864 floats
    unsigned short* attn_bf = (unsigned short*)(part + 1572864);  // 12*512*512
    unsigned short* vcatT   = attn_bf + (size_t)12 * N_ * N_;     // 12*64*512

    hipLaunchKernelGGL(k_logits_pair, dim3(2048), dim3(256), 0, stream,
                       x2d, w_pb, logits);
    hipLaunchKernelGGL(k_proj, dim3(64, 5), dim3(384), 0, stream,
                       x1d, pose_t, pose_r, w_sq, w_sk, w_sv, w_pq, w_pk, w_pv,
                       qs, kst, qp, kpt, vcatT);
    hipLaunchKernelGGL(k_logits_sp, dim3(12 * 128), dim3(256), 0, stream,
                       qs, kst, qp, kpt, bias, tpw, logits);
    hipLaunchKernelGGL(k_softmax, dim3(12 * N_), dim3(256), 0, stream,
                       logits, attn_bf);
    hipLaunchKernelGGL(k_tmp, dim3(N_), dim3(256), 0, stream,
                       logits, x2d, tmp);
    hipLaunchKernelGGL(k_aggr, dim3(12 * 32), dim3(256), 0, stream,
                       attn_bf, vcatT, feat, outpg);
    hipLaunchKernelGGL(k_feat, dim3(N_), dim3(384), 0, stream,
                       tmp, outpg, pose_t, pose_r, w_pairv, feat);
    hipLaunchKernelGGL(k_out_part, dim3(512), dim3(384), 0, stream,
                       feat, w_out, part);
    hipLaunchKernelGGL(k_out_red, dim3(768), dim3(256), 0, stream,
                       part, b_out, out);
}

// Round 5
// 392.280 us; speedup vs baseline: 1.1350x; 1.0078x over previous
//
#include <hip/hip_runtime.h>
#include <hip/hip_bf16.h>
#include <math.h>

#define N_  512
#define D_  384
#define H_  12
#define DK_ 32
#define P_  128

typedef short short8 __attribute__((ext_vector_type(8)));
typedef float f32x4  __attribute__((ext_vector_type(4)));

static __device__ __forceinline__ unsigned short f2bf(float f) {
    union { float f; unsigned int u; } v; v.f = f;
    unsigned int r = (v.u + 0x7FFFu + ((v.u >> 16) & 1u)) >> 16;  // RNE
    return (unsigned short)r;
}

// hardware packed f32x2 -> bf16x2 (v_cvt_pk_bf16_f32)
static __device__ __forceinline__ short2 pk2bf(float a, float b) {
    __hip_bfloat162 h = __float22bfloat162_rn(make_float2(a, b));
    return *(short2*)&h;
}

typedef union { short8 v; short2 h2[4]; } s8u;

// ---------------------------------------------------------------------------
// K1: projections + affine. Grid (64, 5): blockIdx.y = segment
// {0:w_sq, 1:w_sk, 2:w_sv->vcatT, 3:w_pq+w_pk, 4:w_pv->vcatT}.
// ---------------------------------------------------------------------------
__global__ __launch_bounds__(384) void k_proj(
    const float* __restrict__ x1d, const float* __restrict__ pose_t,
    const float* __restrict__ pose_r,
    const float* __restrict__ w_sq, const float* __restrict__ w_sk,
    const float* __restrict__ w_sv, const float* __restrict__ w_pq,
    const float* __restrict__ w_pk, const float* __restrict__ w_pv,
    float* __restrict__ qs, float* __restrict__ kst,
    float* __restrict__ qp, float* __restrict__ kpt,
    unsigned short* __restrict__ vcatT)
{
    const int seg = blockIdx.y;
    const int i0  = blockIdx.x * 8;
    const int t   = threadIdx.x;

    __shared__ float raw[8][288];
    __shared__ float Rsh[8][9];
    __shared__ float Tsh[8][3];

    if (seg < 3) {
        const float* __restrict__ w = (seg == 0) ? w_sq : (seg == 1) ? w_sk : w_sv;
        float acc[8];
        #pragma unroll
        for (int r = 0; r < 8; ++r) acc[r] = 0.f;
        for (int d = 0; d < D_; d += 4) {
            float4 xr[8];
            #pragma unroll
            for (int r = 0; r < 8; ++r)
                xr[r] = *(const float4*)(x1d + (i0 + r) * D_ + d);
            #pragma unroll
            for (int e = 0; e < 4; ++e) {
                float wv = w[(d + e) * D_ + t];
                #pragma unroll
                for (int r = 0; r < 8; ++r)
                    acc[r] += ((const float*)&xr[r])[e] * wv;
            }
        }
        if (seg == 0) {
            #pragma unroll
            for (int r = 0; r < 8; ++r) qs[(i0 + r) * D_ + t] = acc[r];
        } else if (seg == 1) {
            *(float4*)(kst + t * N_ + i0)     = make_float4(acc[0], acc[1], acc[2], acc[3]);
            *(float4*)(kst + t * N_ + i0 + 4) = make_float4(acc[4], acc[5], acc[6], acc[7]);
        } else {
            int h = t >> 5, c = t & 31;
            s8u sv;
            #pragma unroll
            for (int r = 0; r < 4; ++r) sv.h2[r] = pk2bf(acc[2*r], acc[2*r+1]);
            *(short8*)(vcatT + ((size_t)h * 64 + c) * N_ + i0) = sv.v;
        }
    } else {
        if (t < 72) Rsh[t / 9][t % 9] = pose_r[(i0 + t / 9) * 9 + t % 9];
        else if (t < 96) {
            int r = (t - 72) / 3, c = (t - 72) % 3;
            Tsh[r][c] = pose_t[(i0 + r) * 3 + c];
        }

        if (t < 288) {
            const float* __restrict__ w;
            int col, ldw;
            if (seg == 3) {
                if (t < 144) { w = w_pq; col = t;       ldw = 144; }
                else         { w = w_pk; col = t - 144; ldw = 144; }
            } else         { w = w_pv; col = t;       ldw = 288; }
            float acc[8];
            #pragma unroll
            for (int r = 0; r < 8; ++r) acc[r] = 0.f;
            for (int d = 0; d < D_; d += 4) {
                float4 xr[8];
                #pragma unroll
                for (int r = 0; r < 8; ++r)
                    xr[r] = *(const float4*)(x1d + (i0 + r) * D_ + d);
                #pragma unroll
                for (int e = 0; e < 4; ++e) {
                    float wv = w[(d + e) * ldw + col];
                    #pragma unroll
                    for (int r = 0; r < 8; ++r)
                        acc[r] += ((const float*)&xr[r])[e] * wv;
                }
            }
            #pragma unroll
            for (int r = 0; r < 8; ++r) raw[r][t] = acc[r];
        }
        __syncthreads();

        if (t < 288) {
            const int x3   = t % 3;
            const int base = t - x3;
            if (seg == 3) {
                const int c = (t < 144) ? t : t - 144;
                if (t < 144) {
                    #pragma unroll
                    for (int r = 0; r < 8; ++r) {
                        float g = Rsh[r][0 + x3] * raw[r][base]
                                + Rsh[r][3 + x3] * raw[r][base + 1]
                                + Rsh[r][6 + x3] * raw[r][base + 2] + Tsh[r][x3];
                        qp[(i0 + r) * 144 + c] = g;
                    }
                } else {
                    float g[8];
                    #pragma unroll
                    for (int r = 0; r < 8; ++r)
                        g[r] = Rsh[r][0 + x3] * raw[r][base]
                             + Rsh[r][3 + x3] * raw[r][base + 1]
                             + Rsh[r][6 + x3] * raw[r][base + 2] + Tsh[r][x3];
                    *(float4*)(kpt + c * N_ + i0)     = make_float4(g[0], g[1], g[2], g[3]);
                    *(float4*)(kpt + c * N_ + i0 + 4) = make_float4(g[4], g[5], g[6], g[7]);
                }
            } else {
                int h = t / 24, pc = t % 24;
                float g[8];
                #pragma unroll
                for (int r = 0; r < 8; ++r)
                    g[r] = Rsh[r][0 + x3] * raw[r][base]
                         + Rsh[r][3 + x3] * raw[r][base + 1]
                         + Rsh[r][6 + x3] * raw[r][base + 2] + Tsh[r][x3];
                s8u sv;
                #pragma unroll
                for (int r = 0; r < 4; ++r) sv.h2[r] = pk2bf(g[2*r], g[2*r+1]);
                *(short8*)(vcatT + ((size_t)h * 64 + 32 + pc) * N_ + i0) = sv.v;
            }
        }
    }
}

// ---------------------------------------------------------------------------
// K2a: pair-bias logits via MFMA bf16 (pure GEMM), packed bf16 conversion.
// ---------------------------------------------------------------------------
__global__ __launch_bounds__(256) void k_logits_pair(
    const float* __restrict__ x2d, const float* __restrict__ w_pb,
    float* __restrict__ logits)
{
    const int t    = threadIdx.x;
    const int wid  = t >> 6;
    const int lane = t & 63;
    const int quad = lane >> 4;
    const int col  = lane & 15;
    const float pair_w = 0.57735027f;

    short8 bfr[4];
    #pragma unroll
    for (int kt = 0; kt < 4; ++kt) {
        #pragma unroll
        for (int jj = 0; jj < 8; ++jj) {
            int p = kt * 32 + quad * 8 + jj;
            bfr[kt][jj] = (col < 12) ? (short)f2bf(w_pb[p * 12 + col]) : (short)0;
        }
    }

    #pragma unroll
    for (int s = 0; s < 2; ++s) {
        const int T  = blockIdx.x * 8 + wid * 2 + s;
        const int i  = T >> 5;
        const int j0 = (T & 31) << 4;
        const float* xrow = x2d + ((size_t)(i * N_) + j0 + col) * P_;

        f32x4 acc = {0.f, 0.f, 0.f, 0.f};
        #pragma unroll
        for (int kt = 0; kt < 4; ++kt) {
            const int k0 = kt * 32 + quad * 8;
            float4 f0 = *(const float4*)(xrow + k0);
            float4 f1 = *(const float4*)(xrow + k0 + 4);
            s8u afr;
            afr.h2[0] = pk2bf(f0.x, f0.y);
            afr.h2[1] = pk2bf(f0.z, f0.w);
            afr.h2[2] = pk2bf(f1.x, f1.y);
            afr.h2[3] = pk2bf(f1.z, f1.w);
            acc = __builtin_amdgcn_mfma_f32_16x16x32_bf16(afr.v, bfr[kt], acc, 0, 0, 0);
        }
        if (col < 12) {
            #pragma unroll
            for (int r = 0; r < 4; ++r) {
                int j = j0 + quad * 4 + r;
                logits[((size_t)(col * N_ + i)) * N_ + j] = pair_w * acc[r];
            }
        }
    }
}

// ---------------------------------------------------------------------------
// K2b: scalar + point + bias logits, accumulates onto pair logits.
// ---------------------------------------------------------------------------
__global__ __launch_bounds__(256) void k_logits_sp(
    const float* __restrict__ qs, const float* __restrict__ kst,
    const float* __restrict__ qp, const float* __restrict__ kpt,
    const float* __restrict__ bias, const float* __restrict__ tpw,
    float* __restrict__ logits)
{
    const int h  = blockIdx.x / 128;
    const int i0 = (blockIdx.x % 128) * 4;
    const int t  = threadIdx.x;
    __shared__ float qsh[4][32];
    __shared__ float qph[4][12];
    if (t < 128) { int il = t / 32, c = t % 32; qsh[il][c] = qs[(i0+il) * D_ + h*32 + c]; }
    else if (t < 176) { int r = t - 128; int il = r / 12, c = r % 12; qph[il][c] = qp[(i0+il)*144 + h*12 + c]; }
    const float pwh = 0.13608276f * log1pf(expf(tpw[h]));
    const float scalar_w = 0.10206207f;
    __syncthreads();

    for (int jh = 0; jh < 2; ++jh) {
        int j = t + jh * 256;
        float kv[32];
        #pragma unroll
        for (int c = 0; c < 32; ++c) kv[c] = kst[(h*32 + c) * N_ + j];
        float kp[12];
        #pragma unroll
        for (int c = 0; c < 12; ++c) kp[c] = kpt[(h*12 + c) * N_ + j];

        #pragma unroll
        for (int il = 0; il < 4; ++il) {
            float s = 0.f;
            #pragma unroll
            for (int c = 0; c < 32; ++c) s += qsh[il][c] * kv[c];
            float dsum = 0.f;
            #pragma unroll
            for (int p = 0; p < 4; ++p) {
                float dx = qph[il][p*3+0] - kp[p*3+0];
                float dy = qph[il][p*3+1] - kp[p*3+1];
                float dz = qph[il][p*3+2] - kp[p*3+2];
                dsum += sqrtf(dx*dx + dy*dy + dz*dz);
            }
            size_t idx = ((size_t)(h * N_ + (i0+il))) * N_ + j;
            logits[idx] += scalar_w * s - 0.5f * pwh * dsum + bias[(i0+il) * N_ + j];
        }
    }
}

// ---------------------------------------------------------------------------
// K3: softmax (in-place fp32) + bf16 attn copy.
// ---------------------------------------------------------------------------
__global__ __launch_bounds__(256) void k_softmax(float* __restrict__ logits,
                                                 unsigned short* __restrict__ attn_bf)
{
    const int row = blockIdx.x;       // h*512 + i
    const int t = threadIdx.x;
    float* ptr = logits + (size_t)row * N_;
    __shared__ float red[256];

    float a = ptr[t], b = ptr[t + 256];
    red[t] = fmaxf(a, b);
    __syncthreads();
    for (int s = 128; s > 0; s >>= 1) {
        if (t < s) red[t] = fmaxf(red[t], red[t + s]);
        __syncthreads();
    }
    float m = red[0];
    __syncthreads();
    float ea = __expf(a - m), eb = __expf(b - m);
    red[t] = ea + eb;
    __syncthreads();
    for (int s = 128; s > 0; s >>= 1) {
        if (t < s) red[t] += red[t + s];
        __syncthreads();
    }
    float inv = 1.0f / red[0];
    float pa = ea * inv, pb = eb * inv;
    ptr[t]       = pa;
    ptr[t + 256] = pb;
    attn_bf[(size_t)row * N_ + t]       = f2bf(pa);
    attn_bf[(size_t)row * N_ + t + 256] = f2bf(pb);
}

// ---------------------------------------------------------------------------
// K4: tmp[i][h*128+p] = sum_j attn[h,i,j] * x2d[i,j,p].
// float2-per-thread over p halves LDS instruction count vs R2 form;
// 4 j-phases reduced through LDS at the end.
// ---------------------------------------------------------------------------
__global__ __launch_bounds__(256) void k_tmp(
    const float* __restrict__ attn, const float* __restrict__ x2d,
    float* __restrict__ tmp)
{
    const int i = blockIdx.x;
    const int t = threadIdx.x;
    __shared__ float4 at[3][N_];      // [g][j], heads 4g..4g+3 packed
    __shared__ float red[4][1536];

    // stage attn: 12 heads x 512 j, float4 over j
    for (int idx = t; idx < 12 * 128; idx += 256) {
        int h = idx >> 7, j4 = (idx & 127) << 2;
        float4 a = *(const float4*)(attn + ((size_t)(h * N_ + i)) * N_ + j4);
        int g = h >> 2, c = h & 3;
        ((float*)&at[g][j4 + 0])[c] = a.x;
        ((float*)&at[g][j4 + 1])[c] = a.y;
        ((float*)&at[g][j4 + 2])[c] = a.z;
        ((float*)&at[g][j4 + 3])[c] = a.w;
    }
    __syncthreads();

    const int p2 = (t & 63) * 2;
    const int jh = t >> 6;
    float acc[12][2];
    #pragma unroll
    for (int h = 0; h < 12; ++h) { acc[h][0] = 0.f; acc[h][1] = 0.f; }
    const float* xb = x2d + (size_t)i * N_ * P_;

    #pragma unroll 4
    for (int j = jh; j < N_; j += 4) {
        float2 x = *(const float2*)(xb + j * P_ + p2);
        float4 a0 = at[0][j], a1 = at[1][j], a2 = at[2][j];
        acc[0][0]  += a0.x*x.x; acc[0][1]  += a0.x*x.y;
        acc[1][0]  += a0.y*x.x; acc[1][1]  += a0.y*x.y;
        acc[2][0]  += a0.z*x.x; acc[2][1]  += a0.z*x.y;
        acc[3][0]  += a0.w*x.x; acc[3][1]  += a0.w*x.y;
        acc[4][0]  += a1.x*x.x; acc[4][1]  += a1.x*x.y;
        acc[5][0]  += a1.y*x.x; acc[5][1]  += a1.y*x.y;
        acc[6][0]  += a1.z*x.x; acc[6][1]  += a1.z*x.y;
        acc[7][0]  += a1.w*x.x; acc[7][1]  += a1.w*x.y;
        acc[8][0]  += a2.x*x.x; acc[8][1]  += a2.x*x.y;
        acc[9][0]  += a2.y*x.x; acc[9][1]  += a2.y*x.y;
        acc[10][0] += a2.z*x.x; acc[10][1] += a2.z*x.y;
        acc[11][0] += a2.w*x.x; acc[11][1] += a2.w*x.y;
    }
    #pragma unroll
    for (int h = 0; h < 12; ++h) {
        red[jh][h * 128 + p2]     = acc[h][0];
        red[jh][h * 128 + p2 + 1] = acc[h][1];
    }
    __syncthreads();
    for (int idx = t; idx < 1536; idx += 256)
        tmp[(size_t)i * 1536 + idx] = red[0][idx] + red[1][idx] + red[2][idx] + red[3][idx];
}

// ---------------------------------------------------------------------------
// K5: attn @ [v_s | v_p] via MFMA bf16. Grid 384 = (h, 16-row m-tile).
// ---------------------------------------------------------------------------
__global__ __launch_bounds__(256) void k_aggr(
    const unsigned short* __restrict__ attn_bf,
    const unsigned short* __restrict__ vcatT,
    float* __restrict__ feat, float* __restrict__ outpg)
{
    const int h  = blockIdx.x >> 5;
    const int i0 = (blockIdx.x & 31) << 4;
    const int t    = threadIdx.x;
    const int wid  = t >> 6;
    const int lane = t & 63;
    const int quad = lane >> 4;
    const int col  = lane & 15;
    const int c    = wid * 16 + col;
    const bool cvalid = (c < 56);

    const unsigned short* arow = attn_bf + ((size_t)(h * N_ + i0 + col)) * N_;
    const unsigned short* brow = vcatT + ((size_t)h * 64 + c) * N_;

    f32x4 acc = {0.f, 0.f, 0.f, 0.f};
    #pragma unroll
    for (int kt = 0; kt < 16; ++kt) {
        const int k0 = kt * 32 + quad * 8;
        short8 a = *(const short8*)(arow + k0);
        short8 b;
        if (cvalid) b = *(const short8*)(brow + k0);
        else { b[0]=0;b[1]=0;b[2]=0;b[3]=0;b[4]=0;b[5]=0;b[6]=0;b[7]=0; }
        acc = __builtin_amdgcn_mfma_f32_16x16x32_bf16(a, b, acc, 0, 0, 0);
    }
    #pragma unroll
    for (int r = 0; r < 4; ++r) {
        int i = i0 + quad * 4 + r;
        if (c < 32)       feat[(size_t)i * 1152 + h * 32 + c] = acc[r];
        else if (c < 56)  outpg[((size_t)i * 12 + h) * 24 + (c - 32)] = acc[r];
    }
}

__global__ __launch_bounds__(384) void k_feat(
    const float* __restrict__ tmp, const float* __restrict__ outpg,
    const float* __restrict__ pose_t, const float* __restrict__ pose_r,
    const float* __restrict__ w_pairv, float* __restrict__ feat)
{
    const int i = blockIdx.x;
    const int t = threadIdx.x;
    __shared__ float tsh[1536];
    __shared__ float pg[288];
    __shared__ float pl[288];
    __shared__ float Rsh[9], Tsh[3];

    for (int idx = t; idx < 1536; idx += 384) tsh[idx] = tmp[(size_t)i * 1536 + idx];
    if (t < 288) pg[t] = outpg[i * 288 + t];
    if (t < 9) Rsh[t] = pose_r[i * 9 + t];
    if (t < 3) Tsh[t] = pose_t[i * 3 + t];
    __syncthreads();

    {
        int h = t >> 5;
        const float* ts = tsh + h * 128;
        float acc = 0.f;
        #pragma unroll 4
        for (int p = 0; p < 128; ++p) acc += ts[p] * w_pairv[p * D_ + t];
        feat[(size_t)i * 1152 + 672 + t] = acc;
    }
    if (t < 288) {
        int x3 = t % 3, base = t - x3;
        float g0 = pg[base + 0] - Tsh[0];
        float g1 = pg[base + 1] - Tsh[1];
        float g2 = pg[base + 2] - Tsh[2];
        float v = Rsh[x3*3+0]*g0 + Rsh[x3*3+1]*g1 + Rsh[x3*3+2]*g2;
        pl[t] = v;
        feat[(size_t)i * 1152 + 384 + t] = v;
    }
    __syncthreads();
    if (t < 96) {
        float a = pl[t*3], b = pl[t*3+1], c = pl[t*3+2];
        feat[(size_t)i * 1152 + 1056 + t] = sqrtf(a*a + b*b + c*c);
    }
}

__global__ __launch_bounds__(384) void k_out_part(
    const float* __restrict__ feat, const float* __restrict__ w_out,
    float* __restrict__ part)
{
    const int kc = blockIdx.x >> 6;
    const int i0 = (blockIdx.x & 63) * 8;
    const int t  = threadIdx.x;
    const int k0 = kc * 144;

    float acc[8];
    #pragma unroll
    for (int r = 0; r < 8; ++r) acc[r] = 0.f;

    for (int d = 0; d < 144; d += 4) {
        float4 fr[8];
        #pragma unroll
        for (int r = 0; r < 8; ++r)
            fr[r] = *(const float4*)(feat + (size_t)(i0 + r) * 1152 + k0 + d);
        #pragma unroll
        for (int e = 0; e < 4; ++e) {
            float wv = w_out[(size_t)(k0 + d + e) * D_ + t];
            #pragma unroll
            for (int r = 0; r < 8; ++r)
                acc[r] += ((const float*)&fr[r])[e] * wv;
        }
    }
    #pragma unroll
    for (int r = 0; r < 8; ++r)
        part[((size_t)kc * N_ + i0 + r) * D_ + t] = acc[r];
}

__global__ __launch_bounds__(256) void k_out_red(
    const float* __restrict__ part, const float* __restrict__ b_out,
    float* __restrict__ out)
{
    const int idx = blockIdx.x * 256 + threadIdx.x;
    float s = b_out[idx % D_];
    #pragma unroll
    for (int kc = 0; kc < 8; ++kc) s += part[(size_t)kc * (N_ * D_) + idx];
    out[idx] = s;
}

extern "C" void kernel_launch(void* const* d_in, const int* in_sizes, int n_in,
                              void* d_out, int out_size, void* d_ws, size_t ws_size,
                              hipStream_t stream)
{
    (void)in_sizes; (void)n_in; (void)out_size; (void)ws_size;
    const float* x1d     = (const float*)d_in[0];
    const float* x2d     = (const float*)d_in[1];
    const float* pose_t  = (const float*)d_in[2];
    const float* pose_r  = (const float*)d_in[3];
    const float* bias    = (const float*)d_in[4];
    const float* w_sq    = (const float*)d_in[5];
    const float* w_sk    = (const float*)d_in[6];
    const float* w_sv    = (const float*)d_in[7];
    const float* w_pb    = (const float*)d_in[8];
    const float* w_pq    = (const float*)d_in[9];
    const float* w_pk    = (const float*)d_in[10];
    const float* w_pv    = (const float*)d_in[11];
    const float* tpw     = (const float*)d_in[12];
    const float* w_pairv = (const float*)d_in[13];
    const float* w_out   = (const float*)d_in[14];
    const float* b_out   = (const float*)d_in[15];
    float* out = (float*)d_out;

    float* ws = (float*)d_ws;
    float* qs     = ws;
    float* kst    = qs     + 196608;
    float* qp     = kst    + 196608;
    float* kpt    = qp     + 73728;
    float* logits = kpt    + 73728;
    float* tmp    = logits + 3145728;
    float* outpg  = tmp    + 786432;
    float* feat   = outpg  + 147456;
    float* part   = feat   + 589824;   // 1572864 floats
    unsigned short* attn_bf = (unsigned short*)(part + 1572864);  // 12*512*512
    unsigned short* vcatT   = attn_bf + (size_t)12 * N_ * N_;     // 12*64*512

    hipLaunchKernelGGL(k_logits_pair, dim3(2048), dim3(256), 0, stream,
                       x2d, w_pb, logits);
    hipLaunchKernelGGL(k_proj, dim3(64, 5), dim3(384), 0, stream,
                       x1d, pose_t, pose_r, w_sq, w_sk, w_sv, w_pq, w_pk, w_pv,
                       qs, kst, qp, kpt, vcatT);
    hipLaunchKernelGGL(k_logits_sp, dim3(12 * 128), dim3(256), 0, stream,
                       qs, kst, qp, kpt, bias, tpw, logits);
    hipLaunchKernelGGL(k_softmax, dim3(12 * N_), dim3(256), 0, stream,
                       logits, attn_bf);
    hipLaunchKernelGGL(k_tmp, dim3(N_), dim3(256), 0, stream,
                       logits, x2d, tmp);
    hipLaunchKernelGGL(k_aggr, dim3(12 * 32), dim3(256), 0, stream,
                       attn_bf, vcatT, feat, outpg);
    hipLaunchKernelGGL(k_feat, dim3(N_), dim3(384), 0, stream,
                       tmp, outpg, pose_t, pose_r, w_pairv, feat);
    hipLaunchKernelGGL(k_out_part, dim3(512), dim3(384), 0, stream,
                       feat, w_out, part);
    hipLaunchKernelGGL(k_out_red, dim3(768), dim3(256), 0, stream,
                       part, b_out, out);
}

// Round 6
// 358.926 us; speedup vs baseline: 1.2405x; 1.0929x over previous
//
#include <hip/hip_runtime.h>
#include <hip/hip_bf16.h>
#include <math.h>

#define N_  512
#define D_  384
#define H_  12
#define DK_ 32
#define P_  128

typedef short short8 __attribute__((ext_vector_type(8)));
typedef float f32x4  __attribute__((ext_vector_type(4)));

static __device__ __forceinline__ unsigned short f2bf(float f) {
    union { float f; unsigned int u; } v; v.f = f;
    unsigned int r = (v.u + 0x7FFFu + ((v.u >> 16) & 1u)) >> 16;  // RNE
    return (unsigned short)r;
}
static __device__ __forceinline__ float bf2f(unsigned short u) {
    union { unsigned int u; float f; } v; v.u = ((unsigned int)u) << 16;
    return v.f;
}
static __device__ __forceinline__ short2 pk2bf(float a, float b) {
    __hip_bfloat162 h = __float22bfloat162_rn(make_float2(a, b));
    return *(short2*)&h;
}
typedef union { short8 v; short2 h2[4]; } s8u;

// ---------------------------------------------------------------------------
// K1 (merged): blocks 0..2047 = pair-bias logits MFMA GEMM (t<256 active);
// blocks 2048..2367 = projections+affine (seg = (b-2048)/64).
// ---------------------------------------------------------------------------
__global__ __launch_bounds__(384) void k_front(
    const float* __restrict__ x2d, const float* __restrict__ w_pb,
    float* __restrict__ pairlog,
    const float* __restrict__ x1d, const float* __restrict__ pose_t,
    const float* __restrict__ pose_r,
    const float* __restrict__ w_sq, const float* __restrict__ w_sk,
    const float* __restrict__ w_sv, const float* __restrict__ w_pq,
    const float* __restrict__ w_pk, const float* __restrict__ w_pv,
    float* __restrict__ qs, float* __restrict__ kst,
    float* __restrict__ qp, float* __restrict__ kpt,
    unsigned short* __restrict__ vcatT)
{
    __shared__ float raw[8][288];
    __shared__ float Rsh[8][9];
    __shared__ float Tsh[8][3];

    const int t = threadIdx.x;

    if (blockIdx.x < 2048) {
        // ---------------- pair-bias logits (MFMA) ----------------
        if (t >= 256) return;
        const int wid  = t >> 6;
        const int lane = t & 63;
        const int quad = lane >> 4;
        const int col  = lane & 15;
        const float pair_w = 0.57735027f;

        short8 bfr[4];
        #pragma unroll
        for (int kt = 0; kt < 4; ++kt) {
            #pragma unroll
            for (int jj = 0; jj < 8; ++jj) {
                int p = kt * 32 + quad * 8 + jj;
                bfr[kt][jj] = (col < 12) ? (short)f2bf(w_pb[p * 12 + col]) : (short)0;
            }
        }
        #pragma unroll
        for (int s = 0; s < 2; ++s) {
            const int T  = blockIdx.x * 8 + wid * 2 + s;
            const int i  = T >> 5;
            const int j0 = (T & 31) << 4;
            const float* xrow = x2d + ((size_t)(i * N_) + j0 + col) * P_;

            f32x4 acc = {0.f, 0.f, 0.f, 0.f};
            #pragma unroll
            for (int kt = 0; kt < 4; ++kt) {
                const int k0 = kt * 32 + quad * 8;
                float4 f0 = *(const float4*)(xrow + k0);
                float4 f1 = *(const float4*)(xrow + k0 + 4);
                s8u afr;
                afr.h2[0] = pk2bf(f0.x, f0.y);
                afr.h2[1] = pk2bf(f0.z, f0.w);
                afr.h2[2] = pk2bf(f1.x, f1.y);
                afr.h2[3] = pk2bf(f1.z, f1.w);
                acc = __builtin_amdgcn_mfma_f32_16x16x32_bf16(afr.v, bfr[kt], acc, 0, 0, 0);
            }
            if (col < 12) {
                #pragma unroll
                for (int r = 0; r < 4; ++r) {
                    int j = j0 + quad * 4 + r;
                    pairlog[((size_t)(col * N_ + i)) * N_ + j] = pair_w * acc[r];
                }
            }
        }
        return;
    }

    // ---------------- projections + affine ----------------
    const int b   = blockIdx.x - 2048;
    const int seg = b >> 6;
    const int i0  = (b & 63) * 8;

    if (seg < 3) {
        const float* __restrict__ w = (seg == 0) ? w_sq : (seg == 1) ? w_sk : w_sv;
        float acc[8];
        #pragma unroll
        for (int r = 0; r < 8; ++r) acc[r] = 0.f;
        for (int d = 0; d < D_; d += 4) {
            float4 xr[8];
            #pragma unroll
            for (int r = 0; r < 8; ++r)
                xr[r] = *(const float4*)(x1d + (i0 + r) * D_ + d);
            #pragma unroll
            for (int e = 0; e < 4; ++e) {
                float wv = w[(d + e) * D_ + t];
                #pragma unroll
                for (int r = 0; r < 8; ++r)
                    acc[r] += ((const float*)&xr[r])[e] * wv;
            }
        }
        if (seg == 0) {
            #pragma unroll
            for (int r = 0; r < 8; ++r) qs[(i0 + r) * D_ + t] = acc[r];
        } else if (seg == 1) {
            *(float4*)(kst + t * N_ + i0)     = make_float4(acc[0], acc[1], acc[2], acc[3]);
            *(float4*)(kst + t * N_ + i0 + 4) = make_float4(acc[4], acc[5], acc[6], acc[7]);
        } else {
            int h = t >> 5, c = t & 31;
            s8u sv;
            #pragma unroll
            for (int r = 0; r < 4; ++r) sv.h2[r] = pk2bf(acc[2*r], acc[2*r+1]);
            *(short8*)(vcatT + ((size_t)h * 64 + c) * N_ + i0) = sv.v;
        }
    } else {
        if (t < 72) Rsh[t / 9][t % 9] = pose_r[(i0 + t / 9) * 9 + t % 9];
        else if (t < 96) {
            int r = (t - 72) / 3, c = (t - 72) % 3;
            Tsh[r][c] = pose_t[(i0 + r) * 3 + c];
        }

        if (t < 288) {
            const float* __restrict__ w;
            int col, ldw;
            if (seg == 3) {
                if (t < 144) { w = w_pq; col = t;       ldw = 144; }
                else         { w = w_pk; col = t - 144; ldw = 144; }
            } else         { w = w_pv; col = t;       ldw = 288; }
            float acc[8];
            #pragma unroll
            for (int r = 0; r < 8; ++r) acc[r] = 0.f;
            for (int d = 0; d < D_; d += 4) {
                float4 xr[8];
                #pragma unroll
                for (int r = 0; r < 8; ++r)
                    xr[r] = *(const float4*)(x1d + (i0 + r) * D_ + d);
                #pragma unroll
                for (int e = 0; e < 4; ++e) {
                    float wv = w[(d + e) * ldw + col];
                    #pragma unroll
                    for (int r = 0; r < 8; ++r)
                        acc[r] += ((const float*)&xr[r])[e] * wv;
                }
            }
            #pragma unroll
            for (int r = 0; r < 8; ++r) raw[r][t] = acc[r];
        }
        __syncthreads();

        if (t < 288) {
            const int x3   = t % 3;
            const int base = t - x3;
            if (seg == 3) {
                const int c = (t < 144) ? t : t - 144;
                if (t < 144) {
                    #pragma unroll
                    for (int r = 0; r < 8; ++r) {
                        float g = Rsh[r][0 + x3] * raw[r][base]
                                + Rsh[r][3 + x3] * raw[r][base + 1]
                                + Rsh[r][6 + x3] * raw[r][base + 2] + Tsh[r][x3];
                        qp[(i0 + r) * 144 + c] = g;
                    }
                } else {
                    float g[8];
                    #pragma unroll
                    for (int r = 0; r < 8; ++r)
                        g[r] = Rsh[r][0 + x3] * raw[r][base]
                             + Rsh[r][3 + x3] * raw[r][base + 1]
                             + Rsh[r][6 + x3] * raw[r][base + 2] + Tsh[r][x3];
                    *(float4*)(kpt + c * N_ + i0)     = make_float4(g[0], g[1], g[2], g[3]);
                    *(float4*)(kpt + c * N_ + i0 + 4) = make_float4(g[4], g[5], g[6], g[7]);
                }
            } else {
                int h = t / 24, pc = t % 24;
                float g[8];
                #pragma unroll
                for (int r = 0; r < 8; ++r)
                    g[r] = Rsh[r][0 + x3] * raw[r][base]
                         + Rsh[r][3 + x3] * raw[r][base + 1]
                         + Rsh[r][6 + x3] * raw[r][base + 2] + Tsh[r][x3];
                s8u sv;
                #pragma unroll
                for (int r = 0; r < 4; ++r) sv.h2[r] = pk2bf(g[2*r], g[2*r+1]);
                *(short8*)(vcatT + ((size_t)h * 64 + 32 + pc) * N_ + i0) = sv.v;
            }
        }
    }
}

// ---------------------------------------------------------------------------
// K2 (fused): scalar+point+bias logits + pair logits read + softmax,
// all in registers. Writes ONLY bf16 attn. Block = (h, 4 rows), 256 thr.
// ---------------------------------------------------------------------------
__global__ __launch_bounds__(256) void k_sp_soft(
    const float* __restrict__ qs, const float* __restrict__ kst,
    const float* __restrict__ qp, const float* __restrict__ kpt,
    const float* __restrict__ bias, const float* __restrict__ tpw,
    const float* __restrict__ pairlog,
    unsigned short* __restrict__ attn_bf)
{
    const int h  = blockIdx.x / 128;
    const int i0 = (blockIdx.x % 128) * 4;
    const int t  = threadIdx.x;
    const int lane = t & 63;
    const int wid  = t >> 6;
    __shared__ float qsh[4][32];
    __shared__ float qph[4][12];
    __shared__ float wredm[4][4];
    __shared__ float wreds[4][4];
    if (t < 128) { int il = t / 32, c = t % 32; qsh[il][c] = qs[(i0+il) * D_ + h*32 + c]; }
    else if (t < 176) { int r = t - 128; int il = r / 12, c = r % 12; qph[il][c] = qp[(i0+il)*144 + h*12 + c]; }
    const float pwh = 0.13608276f * log1pf(expf(tpw[h]));
    const float scalar_w = 0.10206207f;
    __syncthreads();

    float v[4][2];
    for (int jh = 0; jh < 2; ++jh) {
        int j = t + jh * 256;
        float kv[32];
        #pragma unroll
        for (int c = 0; c < 32; ++c) kv[c] = kst[(h*32 + c) * N_ + j];
        float kp[12];
        #pragma unroll
        for (int c = 0; c < 12; ++c) kp[c] = kpt[(h*12 + c) * N_ + j];

        #pragma unroll
        for (int il = 0; il < 4; ++il) {
            float s = 0.f;
            #pragma unroll
            for (int c = 0; c < 32; ++c) s += qsh[il][c] * kv[c];
            float dsum = 0.f;
            #pragma unroll
            for (int p = 0; p < 4; ++p) {
                float dx = qph[il][p*3+0] - kp[p*3+0];
                float dy = qph[il][p*3+1] - kp[p*3+1];
                float dz = qph[il][p*3+2] - kp[p*3+2];
                dsum += sqrtf(dx*dx + dy*dy + dz*dz);
            }
            v[il][jh] = scalar_w * s - 0.5f * pwh * dsum
                      + bias[(i0+il) * N_ + j]
                      + pairlog[((size_t)(h * N_ + (i0+il))) * N_ + j];
        }
    }

    // row max
    #pragma unroll
    for (int il = 0; il < 4; ++il) {
        float mt = fmaxf(v[il][0], v[il][1]);
        #pragma unroll
        for (int off = 1; off < 64; off <<= 1)
            mt = fmaxf(mt, __shfl_xor(mt, off));
        if (lane == 0) wredm[il][wid] = mt;
    }
    __syncthreads();
    float m[4];
    #pragma unroll
    for (int il = 0; il < 4; ++il)
        m[il] = fmaxf(fmaxf(wredm[il][0], wredm[il][1]),
                      fmaxf(wredm[il][2], wredm[il][3]));

    // exp + row sum
    #pragma unroll
    for (int il = 0; il < 4; ++il) {
        float e0 = __expf(v[il][0] - m[il]);
        float e1 = __expf(v[il][1] - m[il]);
        v[il][0] = e0; v[il][1] = e1;
        float st = e0 + e1;
        #pragma unroll
        for (int off = 1; off < 64; off <<= 1)
            st += __shfl_xor(st, off);
        if (lane == 0) wreds[il][wid] = st;
    }
    __syncthreads();
    #pragma unroll
    for (int il = 0; il < 4; ++il) {
        float inv = 1.0f / (wreds[il][0] + wreds[il][1] + wreds[il][2] + wreds[il][3]);
        size_t base = ((size_t)(h * N_ + i0 + il)) * N_;
        attn_bf[base + t]       = f2bf(v[il][0] * inv);
        attn_bf[base + t + 256] = f2bf(v[il][1] * inv);
    }
}

// ---------------------------------------------------------------------------
// K3 (merged): blocks 0..511 = tmp (attn_bf @ x2d per row i);
// blocks 512..895 = aggr (attn_bf @ vcatT via MFMA).
// ---------------------------------------------------------------------------
__global__ __launch_bounds__(256) void k_mid(
    const unsigned short* __restrict__ attn_bf,
    const float* __restrict__ x2d,
    const unsigned short* __restrict__ vcatT,
    float* __restrict__ tmp,
    float* __restrict__ feat, float* __restrict__ outpg)
{
    __shared__ float4 at[3][N_];
    __shared__ float red[4][1536];

    const int t = threadIdx.x;

    if (blockIdx.x < 512) {
        const int i = blockIdx.x;
        // stage bf16 attn -> fp32 LDS
        for (int idx = t; idx < 12 * N_; idx += 256) {
            int h = idx >> 9, j = idx & 511;
            float a = bf2f(attn_bf[((size_t)(h * N_ + i)) * N_ + j]);
            ((float*)&at[h >> 2][j])[h & 3] = a;
        }
        __syncthreads();

        const int p2 = (t & 63) * 2;
        const int jh = t >> 6;
        float acc[12][2];
        #pragma unroll
        for (int h = 0; h < 12; ++h) { acc[h][0] = 0.f; acc[h][1] = 0.f; }
        const float* xb = x2d + (size_t)i * N_ * P_;

        #pragma unroll 4
        for (int j = jh; j < N_; j += 4) {
            float2 x = *(const float2*)(xb + j * P_ + p2);
            float4 a0 = at[0][j], a1 = at[1][j], a2 = at[2][j];
            acc[0][0]  += a0.x*x.x; acc[0][1]  += a0.x*x.y;
            acc[1][0]  += a0.y*x.x; acc[1][1]  += a0.y*x.y;
            acc[2][0]  += a0.z*x.x; acc[2][1]  += a0.z*x.y;
            acc[3][0]  += a0.w*x.x; acc[3][1]  += a0.w*x.y;
            acc[4][0]  += a1.x*x.x; acc[4][1]  += a1.x*x.y;
            acc[5][0]  += a1.y*x.x; acc[5][1]  += a1.y*x.y;
            acc[6][0]  += a1.z*x.x; acc[6][1]  += a1.z*x.y;
            acc[7][0]  += a1.w*x.x; acc[7][1]  += a1.w*x.y;
            acc[8][0]  += a2.x*x.x; acc[8][1]  += a2.x*x.y;
            acc[9][0]  += a2.y*x.x; acc[9][1]  += a2.y*x.y;
            acc[10][0] += a2.z*x.x; acc[10][1] += a2.z*x.y;
            acc[11][0] += a2.w*x.x; acc[11][1] += a2.w*x.y;
        }
        #pragma unroll
        for (int h = 0; h < 12; ++h) {
            red[jh][h * 128 + p2]     = acc[h][0];
            red[jh][h * 128 + p2 + 1] = acc[h][1];
        }
        __syncthreads();
        for (int idx = t; idx < 1536; idx += 256)
            tmp[(size_t)i * 1536 + idx] = red[0][idx] + red[1][idx] + red[2][idx] + red[3][idx];
        return;
    }

    // ---------------- aggr (MFMA) ----------------
    const int bid  = blockIdx.x - 512;
    const int h    = bid >> 5;
    const int i0   = (bid & 31) << 4;
    const int wid  = t >> 6;
    const int lane = t & 63;
    const int quad = lane >> 4;
    const int col  = lane & 15;
    const int c    = wid * 16 + col;
    const bool cvalid = (c < 56);

    const unsigned short* arow = attn_bf + ((size_t)(h * N_ + i0 + col)) * N_;
    const unsigned short* brow = vcatT + ((size_t)h * 64 + c) * N_;

    f32x4 acc = {0.f, 0.f, 0.f, 0.f};
    #pragma unroll
    for (int kt = 0; kt < 16; ++kt) {
        const int k0 = kt * 32 + quad * 8;
        short8 a = *(const short8*)(arow + k0);
        short8 b;
        if (cvalid) b = *(const short8*)(brow + k0);
        else { b[0]=0;b[1]=0;b[2]=0;b[3]=0;b[4]=0;b[5]=0;b[6]=0;b[7]=0; }
        acc = __builtin_amdgcn_mfma_f32_16x16x32_bf16(a, b, acc, 0, 0, 0);
    }
    #pragma unroll
    for (int r = 0; r < 4; ++r) {
        int i = i0 + quad * 4 + r;
        if (c < 32)       feat[(size_t)i * 1152 + h * 32 + c] = acc[r];
        else if (c < 56)  outpg[((size_t)i * 12 + h) * 24 + (c - 32)] = acc[r];
    }
}

__global__ __launch_bounds__(384) void k_feat(
    const float* __restrict__ tmp, const float* __restrict__ outpg,
    const float* __restrict__ pose_t, const float* __restrict__ pose_r,
    const float* __restrict__ w_pairv, float* __restrict__ feat)
{
    const int i = blockIdx.x;
    const int t = threadIdx.x;
    __shared__ float tsh[1536];
    __shared__ float pg[288];
    __shared__ float pl[288];
    __shared__ float Rsh[9], Tsh[3];

    for (int idx = t; idx < 1536; idx += 384) tsh[idx] = tmp[(size_t)i * 1536 + idx];
    if (t < 288) pg[t] = outpg[i * 288 + t];
    if (t < 9) Rsh[t] = pose_r[i * 9 + t];
    if (t < 3) Tsh[t] = pose_t[i * 3 + t];
    __syncthreads();

    {
        int h = t >> 5;
        const float* ts = tsh + h * 128;
        float acc = 0.f;
        #pragma unroll 4
        for (int p = 0; p < 128; ++p) acc += ts[p] * w_pairv[p * D_ + t];
        feat[(size_t)i * 1152 + 672 + t] = acc;
    }
    if (t < 288) {
        int x3 = t % 3, base = t - x3;
        float g0 = pg[base + 0] - Tsh[0];
        float g1 = pg[base + 1] - Tsh[1];
        float g2 = pg[base + 2] - Tsh[2];
        float v = Rsh[x3*3+0]*g0 + Rsh[x3*3+1]*g1 + Rsh[x3*3+2]*g2;
        pl[t] = v;
        feat[(size_t)i * 1152 + 384 + t] = v;
    }
    __syncthreads();
    if (t < 96) {
        float a = pl[t*3], b = pl[t*3+1], c = pl[t*3+2];
        feat[(size_t)i * 1152 + 1056 + t] = sqrtf(a*a + b*b + c*c);
    }
}

__global__ __launch_bounds__(384) void k_out_part(
    const float* __restrict__ feat, const float* __restrict__ w_out,
    float* __restrict__ part)
{
    const int kc = blockIdx.x >> 6;
    const int i0 = (blockIdx.x & 63) * 8;
    const int t  = threadIdx.x;
    const int k0 = kc * 144;

    float acc[8];
    #pragma unroll
    for (int r = 0; r < 8; ++r) acc[r] = 0.f;

    for (int d = 0; d < 144; d += 4) {
        float4 fr[8];
        #pragma unroll
        for (int r = 0; r < 8; ++r)
            fr[r] = *(const float4*)(feat + (size_t)(i0 + r) * 1152 + k0 + d);
        #pragma unroll
        for (int e = 0; e < 4; ++e) {
            float wv = w_out[(size_t)(k0 + d + e) * D_ + t];
            #pragma unroll
            for (int r = 0; r < 8; ++r)
                acc[r] += ((const float*)&fr[r])[e] * wv;
        }
    }
    #pragma unroll
    for (int r = 0; r < 8; ++r)
        part[((size_t)kc * N_ + i0 + r) * D_ + t] = acc[r];
}

__global__ __launch_bounds__(256) void k_out_red(
    const float* __restrict__ part, const float* __restrict__ b_out,
    float* __restrict__ out)
{
    const int idx = blockIdx.x * 256 + threadIdx.x;
    float s = b_out[idx % D_];
    #pragma unroll
    for (int kc = 0; kc < 8; ++kc) s += part[(size_t)kc * (N_ * D_) + idx];
    out[idx] = s;
}

extern "C" void kernel_launch(void* const* d_in, const int* in_sizes, int n_in,
                              void* d_out, int out_size, void* d_ws, size_t ws_size,
                              hipStream_t stream)
{
    (void)in_sizes; (void)n_in; (void)out_size; (void)ws_size;
    const float* x1d     = (const float*)d_in[0];
    const float* x2d     = (const float*)d_in[1];
    const float* pose_t  = (const float*)d_in[2];
    const float* pose_r  = (const float*)d_in[3];
    const float* bias    = (const float*)d_in[4];
    const float* w_sq    = (const float*)d_in[5];
    const float* w_sk    = (const float*)d_in[6];
    const float* w_sv    = (const float*)d_in[7];
    const float* w_pb    = (const float*)d_in[8];
    const float* w_pq    = (const float*)d_in[9];
    const float* w_pk    = (const float*)d_in[10];
    const float* w_pv    = (const float*)d_in[11];
    const float* tpw     = (const float*)d_in[12];
    const float* w_pairv = (const float*)d_in[13];
    const float* w_out   = (const float*)d_in[14];
    const float* b_out   = (const float*)d_in[15];
    float* out = (float*)d_out;

    float* ws = (float*)d_ws;
    float* qs      = ws;
    float* kst     = qs      + 196608;
    float* qp      = kst     + 196608;
    float* kpt     = qp      + 73728;
    float* pairlog = kpt     + 73728;    // 3145728 (only 12*512*512 used)
    float* tmp     = pairlog + 3145728;
    float* outpg   = tmp     + 786432;
    float* feat    = outpg   + 147456;
    float* part    = feat    + 589824;   // 1572864 floats
    unsigned short* attn_bf = (unsigned short*)(part + 1572864);  // 12*512*512
    unsigned short* vcatT   = attn_bf + (size_t)12 * N_ * N_;     // 12*64*512

    hipLaunchKernelGGL(k_front, dim3(2048 + 320), dim3(384), 0, stream,
                       x2d, w_pb, pairlog,
                       x1d, pose_t, pose_r, w_sq, w_sk, w_sv, w_pq, w_pk, w_pv,
                       qs, kst, qp, kpt, vcatT);
    hipLaunchKernelGGL(k_sp_soft, dim3(12 * 128), dim3(256), 0, stream,
                       qs, kst, qp, kpt, bias, tpw, pairlog, attn_bf);
    hipLaunchKernelGGL(k_mid, dim3(512 + 384), dim3(256), 0, stream,
                       attn_bf, x2d, vcatT, tmp, feat, outpg);
    hipLaunchKernelGGL(k_feat, dim3(N_), dim3(384), 0, stream,
                       tmp, outpg, pose_t, pose_r, w_pairv, feat);
    hipLaunchKernelGGL(k_out_part, dim3(512), dim3(384), 0, stream,
                       feat, w_out, part);
    hipLaunchKernelGGL(k_out_red, dim3(768), dim3(256), 0, stream,
                       part, b_out, out);
}